// Round 2
// baseline (248.926 us; speedup 1.0000x reference)
//
#include <hip/hip_runtime.h>
#include <cmath>

#define T_LEN 480000
#define BATCH 64
#define CHUNK 1024
#define WARM  512
#define NCH   ((T_LEN + CHUNK - 1) / CHUNK)   // 469 chunks per row
#define BLKS  32                               // samples per pipeline block (8 x float4)

// One biquad DF1 step. Critical path is a single dependent FMA per sample:
//   g = fma(c2, y2, f)  (y2 is 2 samples old -> off critical path)
//   y = fma(c1, y1, g)
#define STEP(xi, yo) do {                                   \
    float f_  = fmaf(b0, (xi), fmaf(b1, x1, b2 * x2));      \
    float g_  = fmaf(c2, y2, f_);                           \
    float yy_ = fmaf(c1, y1, g_);                           \
    x2 = x1; x1 = (xi);                                     \
    y2 = y1; y1 = yy_;                                      \
    (yo) = yy_;                                             \
} while (0)

__global__ __launch_bounds__(64) void highpass_kernel(
    const float* __restrict__ in, float* __restrict__ out,
    const float b0, const float b1, const float b2,
    const float c1, const float c2)
{
    const int idx = blockIdx.x * blockDim.x + threadIdx.x;
    if (idx >= BATCH * NCH) return;
    const int r = idx / NCH;
    const int c = idx - r * NCH;

    const size_t rowoff = (size_t)r * T_LEN;
    const int begin = c * CHUNK;
    int end = begin + CHUNK; if (end > T_LEN) end = T_LEN;
    int start = begin - WARM; if (start < 0) start = 0;

    const float4* __restrict__ xv = (const float4*)(in  + rowoff + start);
    float4*       __restrict__ yv = (float4*)      (out + rowoff + start);

    const int nblk = (end - start) / BLKS;    // total 32-sample blocks (exact: all spans %32==0)
    const int wblk = (begin - start) / BLKS;  // warm-up blocks (outputs discarded)

    float x1 = 0.f, x2 = 0.f, y1 = 0.f, y2 = 0.f;

    float4 cur[8], nxt[8];
#pragma unroll
    for (int i = 0; i < 8; ++i) cur[i] = xv[i];

    for (int b = 0; b < nblk; ++b) {
        // prefetch next block while computing current (8 KB/wave in flight)
        if (b + 1 < nblk) {
#pragma unroll
            for (int i = 0; i < 8; ++i) nxt[i] = xv[(b + 1) * 8 + i];
        }

        float4 o[8];
#pragma unroll
        for (int i = 0; i < 8; ++i) {
            float4 v = cur[i];
            float4 q;
            STEP(v.x, q.x);
            STEP(v.y, q.y);
            STEP(v.z, q.z);
            STEP(v.w, q.w);
            o[i] = q;
        }

        if (b >= wblk) {
#pragma unroll
            for (int i = 0; i < 8; ++i) yv[b * 8 + i] = o[i];
        }

#pragma unroll
        for (int i = 0; i < 8; ++i) cur[i] = nxt[i];
    }
}

extern "C" void kernel_launch(void* const* d_in, const int* in_sizes, int n_in,
                              void* d_out, int out_size, void* d_ws, size_t ws_size,
                              hipStream_t stream) {
    const float* in  = (const float*)d_in[0];
    float*       out = (float*)d_out;

    // RBJ highpass biquad coefficients (double precision on host, match reference)
    const double Q     = 0.7071067811865476;
    const double w0    = 2.0 * M_PI * 100.0 / 16000.0;
    const double alpha = sin(w0) / (2.0 * Q);
    const double cosw  = cos(w0);
    const double b0d = (1.0 + cosw) / 2.0;
    const double b1d = -(1.0 + cosw);
    const double b2d = b0d;
    const double a0d = 1.0 + alpha;
    const double a1d = -2.0 * cosw;
    const double a2d = 1.0 - alpha;

    const float b0 = (float)(b0d / a0d);
    const float b1 = (float)(b1d / a0d);
    const float b2 = (float)(b2d / a0d);
    const float c1 = (float)(-(a1d / a0d));
    const float c2 = (float)(-(a2d / a0d));

    const int total  = BATCH * NCH;            // 30016 threads = 469 waves
    const int tblock = 64;
    const int grid   = (total + tblock - 1) / tblock;

    hipLaunchKernelGGL(highpass_kernel, dim3(grid), dim3(tblock), 0, stream,
                       in, out, b0, b1, b2, c1, c2);
}